// Round 5
// baseline (193.156 us; speedup 1.0000x reference)
//
#include <hip/hip_runtime.h>

#define BB 16
#define SS 2048
#define NTOK (BB*SS)
#define FF 512
#define EPSF 1e-5f

#if __has_builtin(__builtin_amdgcn_exp2f)
#define EXP2F(x) __builtin_amdgcn_exp2f(x)
#else
#define EXP2F(x) exp2f(x)
#endif

// ---------------- ws float layout ----------------
// X1   : [NTOK][4]                                         @ 0       (131072)
// part : [8][NTOK][8]  per-keyblock partials (padded to 8) @ 131072  (2097152)
// total 2,228,224 floats = 8.9 MB

__device__ __forceinline__ float wred64(float v) {
#pragma unroll
  for (int m = 32; m > 0; m >>= 1) v += __shfl_xor(v, m, 64);
  return v;
}

// sm layout (57 floats, in LDS, computed per attn block):
// 0:M4[16] (bw2*Wq^T Wk)   16:Bk[16] (-.5 bw2 Wk^T Wk)   32:WVO[16] (Wv*Wo)
// 48:ak[4]  52:bvo[4]  56:ck      where bw2 = bw^2 * log2(e)

// feat record: {P[4], VT[4], R}; query-side constant dropped (cancels in softmax)
__device__ __forceinline__ void compute_feat(const float x[4], const float* s,
                                             float* __restrict__ featrec)
{
  float P[4], VT[4], tk[4];
#pragma unroll
  for (int a = 0; a < 4; ++a) {
    P[a]  = fmaf(s[a*4+3], x[3], fmaf(s[a*4+2], x[2], fmaf(s[a*4+1], x[1], s[a*4+0]*x[0])));
    tk[a] = fmaf(s[16+a*4+3], x[3], fmaf(s[16+a*4+2], x[2], fmaf(s[16+a*4+1], x[1], s[16+a*4+0]*x[0])));
    VT[a] = s[52+a] + fmaf(s[32+3*4+a], x[3], fmaf(s[32+2*4+a], x[2], fmaf(s[32+1*4+a], x[1], s[32+0*4+a]*x[0])));
  }
  float R = s[56];
#pragma unroll
  for (int a = 0; a < 4; ++a) R = fmaf(tk[a] + s[48+a], x[a], R);
  float4* fp = (float4*)featrec;
  fp[0] = make_float4(P[0], P[1], P[2], P[3]);
  fp[1] = make_float4(VT[0], VT[1], VT[2], VT[3]);
  fp[2] = make_float4(R, 0.f, 0.f, 0.f);
}

// attention partials: block covers 512 queries x 256 keys.
// The 57-float fused small-matrix is recomputed per block (256 thr = one h each),
// key features computed on the fly during LDS staging, X never materialized for
// layer 0 (KEY/VALUE read directly).
// 4 waves share the 512 queries (8 q/lane); each wave owns 64 of the 256 staged keys.
// Cross-wave LDS reduction (stride 21, gcd(21,32)=1 -> 2-way aliasing, free).
// Weight pointers are pre-offset to this layer's slice.
__global__ __launch_bounds__(256) void attn_kernel(
    const float* __restrict__ KEY, const float* __restrict__ VALUE,
    const float* __restrict__ X,     // used when layer0 == 0
    const float* __restrict__ Wq, const float* __restrict__ bq,
    const float* __restrict__ Wk, const float* __restrict__ bk,
    const float* __restrict__ Wv, const float* __restrict__ bv,
    const float* __restrict__ Wo, const float* __restrict__ bw,
    float* __restrict__ part, int layer0)
{
  __shared__ float smem[512*21];     // 43 KB: key feats [256][12], then reduce buf
  __shared__ float scratch[4*58];    // per-wave smallmat partials
  __shared__ float smL[64];          // final fused small-matrix
  const int bid = blockIdx.x;
  const int b = bid >> 5;
  const int r = bid & 31;
  const int qg = r >> 3, kb = r & 7;
  const int qbase = (b << 11) + (qg << 9);
  const int kbase = (b << 11) + (kb << 8);
  const int tid = threadIdx.x;
  const int lane = tid & 63, wave = tid >> 6;

  // ---- fused small-matrix: thread tid handles h = tid (H = 256 exactly) ----
  {
    const int h = tid;
    float vq[4], vk[4], vv[4], wo4[4];
#pragma unroll
    for (int a = 0; a < 4; ++a) {
      vq[a]  = Wq[a*256 + h];
      vk[a]  = Wk[a*256 + h];
      vv[a]  = Wv[a*256 + h];
      wo4[a] = Wo[h*4 + a];
    }
    const float bqh = bq[h], bkh = bk[h], bvh = bv[h];
    float p[58];
#pragma unroll
    for (int a = 0; a < 4; ++a)
#pragma unroll
      for (int c = 0; c < 4; ++c) {
        p[a*4+c]      = vq[a] * vk[c];
        p[16 + a*4+c] = vk[a] * vk[c];
        p[32 + a*4+c] = vv[a] * wo4[c];
      }
#pragma unroll
    for (int a = 0; a < 4; ++a) {
      p[48+a] = vk[a] * (bqh - bkh);
      p[52+a] = bvh * wo4[a];
    }
    p[56] = bqh * bkh;
    p[57] = bkh * bkh;
#pragma unroll
    for (int t = 0; t < 58; ++t) p[t] = wred64(p[t]);
    if (lane == 0) {
#pragma unroll
      for (int t = 0; t < 58; ++t) scratch[wave*58 + t] = p[t];
    }
  }
  __syncthreads();
  if (tid < 57) {
    const float bwv = bw[0];
    const float bw2 = bwv * bwv * 1.44269504088896f;   // exp2 prescale
    const float raw = scratch[tid] + scratch[58 + tid] + scratch[116 + tid] + scratch[174 + tid];
    float v;
    if (tid < 16)      v = bw2 * raw;
    else if (tid < 32) v = -0.5f * bw2 * raw;
    else if (tid < 48) v = raw;
    else if (tid < 52) v = bw2 * raw;
    else if (tid < 56) v = raw;
    else {
      const float raw57 = scratch[57] + scratch[115] + scratch[173] + scratch[231];
      v = bw2 * (raw - 0.5f * raw57);
    }
    smL[tid] = v;
  }
  __syncthreads();

  // ---- stage 256 key-feature records ----
  {
    const int gk = kbase + tid;
    float xr[4];
    if (layer0) {
      xr[0] = KEY[gk*3 + 0]; xr[1] = KEY[gk*3 + 1]; xr[2] = KEY[gk*3 + 2];
      xr[3] = VALUE[gk];
    } else {
      const float4 xk = *(const float4*)(X + (size_t)gk*4);
      xr[0] = xk.x; xr[1] = xk.y; xr[2] = xk.z; xr[3] = xk.w;
    }
    float fr[12];
    compute_feat(xr, smL, fr);
    float* dst = smem + tid*12;
    ((float4*)dst)[0] = ((float4*)fr)[0];
    ((float4*)dst)[1] = ((float4*)fr)[1];
    dst[8] = fr[8];
  }

  float xq[8][4], acc[8][5];
#pragma unroll
  for (int j = 0; j < 8; ++j) {
    const int gq = qbase + j*64 + lane;
    if (layer0) {
      xq[j][0] = KEY[gq*3 + 0]; xq[j][1] = KEY[gq*3 + 1]; xq[j][2] = KEY[gq*3 + 2];
      xq[j][3] = VALUE[gq];
    } else {
      const float4 xv = *(const float4*)(X + (size_t)gq*4);
      xq[j][0] = xv.x; xq[j][1] = xv.y; xq[j][2] = xv.z; xq[j][3] = xv.w;
    }
#pragma unroll
    for (int c = 0; c < 5; ++c) acc[j][c] = 0.f;
  }
  __syncthreads();

  const float* kf = smem + wave*64*12;
#pragma unroll 2
  for (int k = 0; k < 64; ++k) {
    const float* kp = kf + k*12;
    const float4 P  = *(const float4*)kp;
    const float4 VT = *(const float4*)(kp + 4);
    const float R = kp[8];
#pragma unroll
    for (int j = 0; j < 8; ++j) {
      float l = fmaf(xq[j][3], P.w, fmaf(xq[j][2], P.z,
                fmaf(xq[j][1], P.y, fmaf(xq[j][0], P.x, R))));
      const float e = EXP2F(l);
      acc[j][0] = fmaf(e, VT.x, acc[j][0]);
      acc[j][1] = fmaf(e, VT.y, acc[j][1]);
      acc[j][2] = fmaf(e, VT.z, acc[j][2]);
      acc[j][3] = fmaf(e, VT.w, acc[j][3]);
      acc[j][4] += e;
    }
  }
  __syncthreads();     // key buffer dead; reuse LDS for cross-wave reduction
#pragma unroll
  for (int j = 0; j < 8; ++j) {
    float* rr = smem + (j*64 + lane)*21 + wave*5;
    rr[0] = acc[j][0]; rr[1] = acc[j][1]; rr[2] = acc[j][2];
    rr[3] = acc[j][3]; rr[4] = acc[j][4];
  }
  __syncthreads();
  float* pb = part + (size_t)kb * NTOK * 8;
#pragma unroll
  for (int t = 0; t < 2; ++t) {
    const int q = t*256 + tid;
    const float* rr = smem + q*21;
    float s0 = 0.f, s1 = 0.f, s2 = 0.f, s3 = 0.f, s4 = 0.f;
#pragma unroll
    for (int w = 0; w < 4; ++w) {
      s0 += rr[w*5+0]; s1 += rr[w*5+1]; s2 += rr[w*5+2];
      s3 += rr[w*5+3]; s4 += rr[w*5+4];
    }
    float* pp = pb + (size_t)(qbase + q)*8;
    *(float4*)pp = make_float4(s0, s1, s2, s3);
    pp[4] = s4;
  }
}

__device__ __forceinline__ void ln4(const float t[4], const float* __restrict__ g,
                                    const float* __restrict__ b, float r[4])
{
  const float m = 0.25f*(t[0]+t[1]+t[2]+t[3]);
  const float d0 = t[0]-m, d1 = t[1]-m, d2 = t[2]-m, d3 = t[3]-m;
  const float v = 0.25f*(d0*d0 + d1*d1 + d2*d2 + d3*d3);
  const float sc = rsqrtf(v + EPSF);
  r[0] = fmaf(d0*sc, g[0], b[0]);
  r[1] = fmaf(d1*sc, g[1], b[1]);
  r[2] = fmaf(d2*sc, g[2], b[2]);
  r[3] = fmaf(d3*sc, g[3], b[3]);
}

// combine: block = 512 thr = 64 tokens x 8 F-chunks; fc k reduces part stripe k.
// Reads W1/W2/b1 directly (uniform-address broadcast loads, L2-hot).
// Weight pointers pre-offset to this layer's slice.
__global__ __launch_bounds__(512) void combine_kernel(
    const float* __restrict__ part,
    const float* __restrict__ KEY, const float* __restrict__ VALUE,
    const float* __restrict__ Xin,   // used when layer0 == 0
    const float* __restrict__ W1, const float* __restrict__ b1,
    const float* __restrict__ W2,
    const float* __restrict__ bo, const float* __restrict__ g1, const float* __restrict__ be1,
    const float* __restrict__ b2v, const float* __restrict__ g2, const float* __restrict__ be2,
    float* __restrict__ Xout,
    const float* __restrict__ Wfc, const float* __restrict__ bfc,
    float* __restrict__ outp, int layer0, int last)
{
  const int tok = threadIdx.x & 63, fc = threadIdx.x >> 6;
  const int gq = blockIdx.x*64 + tok;
  __shared__ float redp[8][64][5];
  __shared__ float ress[64][4];
  __shared__ float redf[8][64][4];

  {
    const float* pp = part + ((size_t)fc*NTOK + gq)*8;
    const float4 v = *(const float4*)pp;
    redp[fc][tok][0] = v.x; redp[fc][tok][1] = v.y;
    redp[fc][tok][2] = v.z; redp[fc][tok][3] = v.w;
    redp[fc][tok][4] = pp[4];
  }
  __syncthreads();

  if (fc == 0) {
    float acc[5] = {0,0,0,0,0};
#pragma unroll
    for (int k = 0; k < 8; ++k)
#pragma unroll
      for (int c = 0; c < 5; ++c) acc[c] += redp[k][tok][c];
    const float inv = 1.0f / acc[4];
    float xv[4];
    if (layer0) {
      xv[0] = KEY[gq*3 + 0]; xv[1] = KEY[gq*3 + 1]; xv[2] = KEY[gq*3 + 2];
      xv[3] = VALUE[gq];
    } else {
      const float4 x4 = *(const float4*)(Xin + (size_t)gq*4);
      xv[0] = x4.x; xv[1] = x4.y; xv[2] = x4.z; xv[3] = x4.w;
    }
    float t[4];
    t[0] = xv[0] + fmaf(acc[0], inv, bo[0]);
    t[1] = xv[1] + fmaf(acc[1], inv, bo[1]);
    t[2] = xv[2] + fmaf(acc[2], inv, bo[2]);
    t[3] = xv[3] + fmaf(acc[3], inv, bo[3]);
    float r[4];
    ln4(t, g1, be1, r);
    ress[tok][0] = r[0]; ress[tok][1] = r[1]; ress[tok][2] = r[2]; ress[tok][3] = r[3];
  }
  __syncthreads();

  const float r0 = ress[tok][0], r1 = ress[tok][1], r2 = ress[tok][2], r3 = ress[tok][3];
  float fa[4] = {0,0,0,0};
  const int fbase = fc*64;
#pragma unroll 4
  for (int f0 = 0; f0 < 64; ++f0) {
    const int f = fbase + f0;
    const float w10 = W1[0*FF + f], w11 = W1[1*FF + f],
                w12 = W1[2*FF + f], w13 = W1[3*FF + f];
    const float4 w2r = *(const float4*)(W2 + (size_t)f*4);
    const float b1f = b1[f];
    float h = fmaf(r3, w13, fmaf(r2, w12, fmaf(r1, w11, fmaf(r0, w10, b1f))));
    h = fmaxf(h, 0.f);
    fa[0] = fmaf(h, w2r.x, fa[0]);
    fa[1] = fmaf(h, w2r.y, fa[1]);
    fa[2] = fmaf(h, w2r.z, fa[2]);
    fa[3] = fmaf(h, w2r.w, fa[3]);
  }
  redf[fc][tok][0] = fa[0]; redf[fc][tok][1] = fa[1];
  redf[fc][tok][2] = fa[2]; redf[fc][tok][3] = fa[3];
  __syncthreads();

  if (fc == 0) {
    float t2[4];
#pragma unroll
    for (int c = 0; c < 4; ++c) {
      float s = b2v[c];
#pragma unroll
      for (int k = 0; k < 8; ++k) s += redf[k][tok][c];
      t2[c] = ress[tok][c] + s;
    }
    float y[4];
    ln4(t2, g2, be2, y);
    if (last) {
      outp[gq] = fmaf(y[3], Wfc[3], fmaf(y[2], Wfc[2], fmaf(y[1], Wfc[1], fmaf(y[0], Wfc[0], bfc[0]))));
    } else {
      *(float4*)(Xout + (size_t)gq*4) = make_float4(y[0], y[1], y[2], y[3]);
    }
  }
}

extern "C" void kernel_launch(void* const* d_in, const int* in_sizes, int n_in,
                              void* d_out, int out_size, void* d_ws, size_t ws_size,
                              hipStream_t stream)
{
  const float* KEY   = (const float*)d_in[0];
  const float* VALUE = (const float*)d_in[1];
  const float* Wq  = (const float*)d_in[2];
  const float* bq  = (const float*)d_in[3];
  const float* Wk  = (const float*)d_in[4];
  const float* bk  = (const float*)d_in[5];
  const float* Wv  = (const float*)d_in[6];
  const float* bv  = (const float*)d_in[7];
  const float* Wo  = (const float*)d_in[8];
  const float* bo  = (const float*)d_in[9];
  const float* bw  = (const float*)d_in[10];
  const float* g1  = (const float*)d_in[11];
  const float* be1 = (const float*)d_in[12];
  const float* W1  = (const float*)d_in[13];
  const float* b1  = (const float*)d_in[14];
  const float* W2  = (const float*)d_in[15];
  const float* b2  = (const float*)d_in[16];
  const float* g2  = (const float*)d_in[17];
  const float* be2 = (const float*)d_in[18];
  const float* Wfc = (const float*)d_in[19];
  const float* bfc = (const float*)d_in[20];
  float* out = (float*)d_out;

  float* w    = (float*)d_ws;
  float* X1   = w;              // 131072
  float* part = w + 131072;     // 2097152

  // layer 0 (weights at slice 0)
  attn_kernel<<<512, 256, 0, stream>>>(KEY, VALUE, nullptr,
      Wq, bq, Wk, bk, Wv, bv, Wo, bw, part, 1);
  combine_kernel<<<512, 512, 0, stream>>>(part, KEY, VALUE, nullptr,
      W1, b1, W2, bo, g1, be1, b2, g2, be2,
      X1, Wfc, bfc, out, 1, 0);

  // layer 1 (weights at slice 1)
  attn_kernel<<<512, 256, 0, stream>>>(KEY, VALUE, X1,
      Wq + 1024, bq + 256, Wk + 1024, bk + 256, Wv + 1024, bv + 256,
      Wo + 1024, bw + 1, part, 0);
  combine_kernel<<<512, 512, 0, stream>>>(part, KEY, VALUE, X1,
      W1 + 2048, b1 + FF, W2 + 2048, bo + 4, g1 + 4, be1 + 4, b2 + 4, g2 + 4, be2 + 4,
      nullptr, Wfc, bfc, out, 0, 1);
}

// Round 6
// 182.506 us; speedup vs baseline: 1.0584x; 1.0584x over previous
//
#include <hip/hip_runtime.h>

#define BB 16
#define SS 2048
#define NTOK (BB*SS)
#define FF 512
#define EPSF 1e-5f

#if __has_builtin(__builtin_amdgcn_exp2f)
#define EXP2F(x) __builtin_amdgcn_exp2f(x)
#else
#define EXP2F(x) exp2f(x)
#endif

typedef float v2f __attribute__((ext_vector_type(2)));

// ---------------- ws float layout ----------------
// sm   : [L][64]       fused small mats (exp2-prescaled)   @ 0       (128)
// w1t  : [L][512][12]  {w1col[4], w2row[4], b1, pad3}      @ 128     (12288)
// X0   : [NTOK][4]                                         @ 12416   (131072)
// X1   : [NTOK][4]                                         @ 143488  (131072)
// part : [8][NTOK][8]  per-keyblock partials (padded to 8) @ 274560  (2097152)
// total 2,371,712 floats = 9.5 MB

__device__ __forceinline__ float wred64(float v) {
#pragma unroll
  for (int m = 32; m > 0; m >>= 1) v += __shfl_xor(v, m, 64);
  return v;
}

// sm layout (per layer, stride 64):
// 0:M4[16] (bw2*Wq^T Wk)   16:Bk[16] (-.5 bw2 Wk^T Wk)   32:WVO[16] (Wv*Wo)
// 48:ak[4]  52:bvo[4]  56:ck      where bw2 = bw^2 * log2(e)

// blocks 0..127: build X0 from KEY/VALUE. blocks 128..129: weight prep for layer bid-128.
__global__ __launch_bounds__(256) void prep_kernel(
    const float* __restrict__ KEY, const float* __restrict__ VALUE,
    const float* __restrict__ Wq, const float* __restrict__ bq,
    const float* __restrict__ Wk, const float* __restrict__ bk,
    const float* __restrict__ Wv, const float* __restrict__ bv,
    const float* __restrict__ Wo, const float* __restrict__ bw,
    const float* __restrict__ W1, const float* __restrict__ b1,
    const float* __restrict__ W2,
    float* __restrict__ sm, float* __restrict__ w1t, float* __restrict__ X0)
{
  const int bid = blockIdx.x;
  if (bid < 128) {
    const int gq = bid*256 + threadIdx.x;
    *(float4*)(X0 + (size_t)gq*4) =
        make_float4(KEY[gq*3 + 0], KEY[gq*3 + 1], KEY[gq*3 + 2], VALUE[gq]);
    return;
  }
  const int i = bid - 128;        // layer
  if (threadIdx.x >= 64) return;
  const int lane = threadIdx.x;   // 0..63
  float m4[4][4] = {{0}}, gkk[4][4] = {{0}}, wvo[4][4] = {{0}};
  float akk[4] = {0}, bvo[4] = {0};
  float ck1 = 0.f, ck2 = 0.f;

  for (int h = lane; h < 256; h += 64) {
    float vq[4], vk[4], vv[4], wo4[4];
#pragma unroll
    for (int a = 0; a < 4; ++a) {
      vq[a]  = Wq[(i*4 + a)*256 + h];
      vk[a]  = Wk[(i*4 + a)*256 + h];
      vv[a]  = Wv[(i*4 + a)*256 + h];
      wo4[a] = Wo[(i*256 + h)*4 + a];
    }
    const float bqh = bq[i*256 + h], bkh = bk[i*256 + h], bvh = bv[i*256 + h];
#pragma unroll
    for (int a = 0; a < 4; ++a) {
#pragma unroll
      for (int c = 0; c < 4; ++c) {
        m4[a][c]  = fmaf(vq[a], vk[c], m4[a][c]);
        gkk[a][c] = fmaf(vk[a], vk[c], gkk[a][c]);
        wvo[a][c] = fmaf(vv[a], wo4[c], wvo[a][c]);
      }
      akk[a] = fmaf(vk[a], bqh - bkh, akk[a]);
      bvo[a] = fmaf(bvh, wo4[a], bvo[a]);
    }
    ck1 = fmaf(bqh, bkh, ck1);
    ck2 = fmaf(bkh, bkh, ck2);
  }
#pragma unroll
  for (int a = 0; a < 4; ++a) {
#pragma unroll
    for (int c = 0; c < 4; ++c) {
      m4[a][c]  = wred64(m4[a][c]);
      gkk[a][c] = wred64(gkk[a][c]);
      wvo[a][c] = wred64(wvo[a][c]);
    }
    akk[a] = wred64(akk[a]);
    bvo[a] = wred64(bvo[a]);
  }
  ck1 = wred64(ck1); ck2 = wred64(ck2);

  if (lane == 0) {
    const float bwv = bw[i];
    const float bw2 = bwv * bwv * 1.44269504088896f;   // exp2 prescale
    float* s = sm + i*64;
#pragma unroll
    for (int a = 0; a < 4; ++a) {
#pragma unroll
      for (int c = 0; c < 4; ++c) {
        s[a*4+c]      = bw2 * m4[a][c];
        s[16 + a*4+c] = -0.5f * bw2 * gkk[a][c];
        s[32 + a*4+c] = wvo[a][c];
      }
      s[48+a] = bw2 * akk[a];
      s[52+a] = bvo[a];
    }
    s[56] = bw2 * (ck1 - 0.5f * ck2);
  }
  // FFN weight repack: w1t[f] = {W1[:,f], W2[f,:], b1[f], pad}
  for (int f = lane; f < FF; f += 64) {
    float* rec = w1t + (i*FF + f)*12;
#pragma unroll
    for (int c = 0; c < 4; ++c) rec[c]   = W1[(i*4 + c)*FF + f];
#pragma unroll
    for (int c = 0; c < 4; ++c) rec[4+c] = W2[(i*FF + f)*4 + c];
    rec[8] = b1[i*FF + f];
    rec[9] = 0.f; rec[10] = 0.f; rec[11] = 0.f;
  }
}

// feat record: {P[4], VT[4], R}; query-side constant dropped (cancels in softmax)
__device__ __forceinline__ void compute_feat(const float x[4], const float* __restrict__ s,
                                             float* __restrict__ featrec)
{
  float P[4], VT[4], tk[4];
#pragma unroll
  for (int a = 0; a < 4; ++a) {
    P[a]  = fmaf(s[a*4+3], x[3], fmaf(s[a*4+2], x[2], fmaf(s[a*4+1], x[1], s[a*4+0]*x[0])));
    tk[a] = fmaf(s[16+a*4+3], x[3], fmaf(s[16+a*4+2], x[2], fmaf(s[16+a*4+1], x[1], s[16+a*4+0]*x[0])));
    VT[a] = s[52+a] + fmaf(s[32+3*4+a], x[3], fmaf(s[32+2*4+a], x[2], fmaf(s[32+1*4+a], x[1], s[32+0*4+a]*x[0])));
  }
  float R = s[56];
#pragma unroll
  for (int a = 0; a < 4; ++a) R = fmaf(tk[a] + s[48+a], x[a], R);
  float4* fp = (float4*)featrec;
  fp[0] = make_float4(P[0], P[1], P[2], P[3]);
  fp[1] = make_float4(VT[0], VT[1], VT[2], VT[3]);
  fp[2] = make_float4(R, 0.f, 0.f, 0.f);
}

// attention partials: block covers 512 queries x 256 keys.
// Key features computed on the fly from X during LDS staging (no feat array).
// 4 waves share the 512 queries (8 q/lane, packed in pairs for v_pk_fma_f32);
// each wave owns 64 of the 256 staged keys.
// Cross-wave LDS reduction (stride 21, gcd(21,32)=1 -> 2-way aliasing, free).
__global__ __launch_bounds__(256) void attn_kernel(
    const float* __restrict__ X, const float* __restrict__ sm,
    float* __restrict__ part)
{
  __shared__ float smem[512*21];    // 43 KB; first 3072 floats double as key buffer
  const int bid = blockIdx.x;
  const int b = bid >> 5;
  const int r = bid & 31;
  const int qg = r >> 3, kb = r & 7;
  const int qbase = (b << 11) + (qg << 9);
  const int kbase = (b << 11) + (kb << 8);
  const int tid = threadIdx.x;
  const int lane = tid & 63, wave = tid >> 6;

  // stage 256 key-feature records, computed from X
  {
    const float4 xk = *(const float4*)(X + (size_t)(kbase + tid)*4);
    float xr[4] = {xk.x, xk.y, xk.z, xk.w};
    float fr[12];
    compute_feat(xr, sm, fr);
    float* dst = smem + tid*12;
    ((float4*)dst)[0] = ((float4*)fr)[0];
    ((float4*)dst)[1] = ((float4*)fr)[1];
    dst[8] = fr[8];
  }

  // query pairs: jp covers queries (2jp, 2jp+1); component-packed for pk_fma
  v2f xq2[4][4], axy[8], azw[8], ad[4];
#pragma unroll
  for (int jp = 0; jp < 4; ++jp) {
    const float4 xa = *(const float4*)(X + (size_t)(qbase + (2*jp  )*64 + lane)*4);
    const float4 xb = *(const float4*)(X + (size_t)(qbase + (2*jp+1)*64 + lane)*4);
    xq2[jp][0] = v2f{xa.x, xb.x};
    xq2[jp][1] = v2f{xa.y, xb.y};
    xq2[jp][2] = v2f{xa.z, xb.z};
    xq2[jp][3] = v2f{xa.w, xb.w};
    ad[jp] = v2f{0.f, 0.f};
  }
#pragma unroll
  for (int j = 0; j < 8; ++j) { axy[j] = v2f{0.f, 0.f}; azw[j] = v2f{0.f, 0.f}; }
  __syncthreads();

  const float* kf = smem + wave*64*12;
#pragma unroll 2
  for (int k = 0; k < 64; ++k) {
    const float* kp = kf + k*12;
    const float4 P  = *(const float4*)kp;
    const float4 VT = *(const float4*)(kp + 4);
    const float R = kp[8];
    const v2f Rv  = v2f{R, R};
    const v2f Px  = v2f{P.x, P.x}, Py = v2f{P.y, P.y};
    const v2f Pz  = v2f{P.z, P.z}, Pw = v2f{P.w, P.w};
    const v2f Vxy = v2f{VT.x, VT.y}, Vzw = v2f{VT.z, VT.w};
#pragma unroll
    for (int jp = 0; jp < 4; ++jp) {
      v2f l = __builtin_elementwise_fma(xq2[jp][0], Px, Rv);
      l = __builtin_elementwise_fma(xq2[jp][1], Py, l);
      l = __builtin_elementwise_fma(xq2[jp][2], Pz, l);
      l = __builtin_elementwise_fma(xq2[jp][3], Pw, l);
      const float e0 = EXP2F(l.x);
      const float e1 = EXP2F(l.y);
      const v2f e0v = v2f{e0, e0}, e1v = v2f{e1, e1};
      axy[2*jp  ] = __builtin_elementwise_fma(e0v, Vxy, axy[2*jp  ]);
      azw[2*jp  ] = __builtin_elementwise_fma(e0v, Vzw, azw[2*jp  ]);
      axy[2*jp+1] = __builtin_elementwise_fma(e1v, Vxy, axy[2*jp+1]);
      azw[2*jp+1] = __builtin_elementwise_fma(e1v, Vzw, azw[2*jp+1]);
      ad[jp] += v2f{e0, e1};
    }
  }
  __syncthreads();     // key buffer dead; reuse LDS for cross-wave reduction
#pragma unroll
  for (int j = 0; j < 8; ++j) {
    float* rr = smem + (j*64 + lane)*21 + wave*5;
    rr[0] = axy[j].x; rr[1] = axy[j].y; rr[2] = azw[j].x;
    rr[3] = azw[j].y; rr[4] = (j & 1) ? ad[j>>1].y : ad[j>>1].x;
  }
  __syncthreads();
  float* pb = part + (size_t)kb * NTOK * 8;
#pragma unroll
  for (int t = 0; t < 2; ++t) {
    const int q = t*256 + tid;
    const float* rr = smem + q*21;
    float s0 = 0.f, s1 = 0.f, s2 = 0.f, s3 = 0.f, s4 = 0.f;
#pragma unroll
    for (int w = 0; w < 4; ++w) {
      s0 += rr[w*5+0]; s1 += rr[w*5+1]; s2 += rr[w*5+2];
      s3 += rr[w*5+3]; s4 += rr[w*5+4];
    }
    float* pp = pb + (size_t)(qbase + q)*8;
    *(float4*)pp = make_float4(s0, s1, s2, s3);
    pp[4] = s4;
  }
}

__device__ __forceinline__ void ln4(const float t[4], const float* __restrict__ g,
                                    const float* __restrict__ b, float r[4])
{
  const float m = 0.25f*(t[0]+t[1]+t[2]+t[3]);
  const float d0 = t[0]-m, d1 = t[1]-m, d2 = t[2]-m, d3 = t[3]-m;
  const float v = 0.25f*(d0*d0 + d1*d1 + d2*d2 + d3*d3);
  const float sc = rsqrtf(v + EPSF);
  r[0] = fmaf(d0*sc, g[0], b[0]);
  r[1] = fmaf(d1*sc, g[1], b[1]);
  r[2] = fmaf(d2*sc, g[2], b[2]);
  r[3] = fmaf(d3*sc, g[3], b[3]);
}

// combine: block = 512 thr = 64 tokens x 8 F-chunks; fc k reduces part stripe k
__global__ __launch_bounds__(512) void combine_kernel(
    const float* __restrict__ part, const float* __restrict__ Xin,
    const float* __restrict__ w1t,
    const float* __restrict__ bo, const float* __restrict__ g1, const float* __restrict__ be1,
    const float* __restrict__ b2v, const float* __restrict__ g2, const float* __restrict__ be2,
    float* __restrict__ Xout,
    const float* __restrict__ Wfc, const float* __restrict__ bfc,
    float* __restrict__ outp, int last)
{
  const int tok = threadIdx.x & 63, fc = threadIdx.x >> 6;
  const int gq = blockIdx.x*64 + tok;
  __shared__ float redp[8][64][5];
  __shared__ float ress[64][4];
  __shared__ float redf[8][64][4];

  {
    const float* pp = part + ((size_t)fc*NTOK + gq)*8;
    const float4 v = *(const float4*)pp;
    redp[fc][tok][0] = v.x; redp[fc][tok][1] = v.y;
    redp[fc][tok][2] = v.z; redp[fc][tok][3] = v.w;
    redp[fc][tok][4] = pp[4];
  }
  __syncthreads();

  if (fc == 0) {
    float acc[5] = {0,0,0,0,0};
#pragma unroll
    for (int k = 0; k < 8; ++k)
#pragma unroll
      for (int c = 0; c < 5; ++c) acc[c] += redp[k][tok][c];
    const float inv = 1.0f / acc[4];
    const float4 xv = *(const float4*)(Xin + (size_t)gq*4);
    float t[4];
    t[0] = xv.x + fmaf(acc[0], inv, bo[0]);
    t[1] = xv.y + fmaf(acc[1], inv, bo[1]);
    t[2] = xv.z + fmaf(acc[2], inv, bo[2]);
    t[3] = xv.w + fmaf(acc[3], inv, bo[3]);
    float r[4];
    ln4(t, g1, be1, r);
    ress[tok][0] = r[0]; ress[tok][1] = r[1]; ress[tok][2] = r[2]; ress[tok][3] = r[3];
  }
  __syncthreads();

  const float r0 = ress[tok][0], r1 = ress[tok][1], r2 = ress[tok][2], r3 = ress[tok][3];
  float fa[4] = {0,0,0,0};
  const float* wt = w1t + (size_t)fc*64*12;
#pragma unroll 4
  for (int f = 0; f < 64; ++f) {
    const float* rec = wt + f*12;
    const float4 w1r = *(const float4*)rec;
    const float4 w2r = *(const float4*)(rec + 4);
    const float b1f = rec[8];
    float h = fmaf(r3, w1r.w, fmaf(r2, w1r.z, fmaf(r1, w1r.y, fmaf(r0, w1r.x, b1f))));
    h = fmaxf(h, 0.f);
    fa[0] = fmaf(h, w2r.x, fa[0]);
    fa[1] = fmaf(h, w2r.y, fa[1]);
    fa[2] = fmaf(h, w2r.z, fa[2]);
    fa[3] = fmaf(h, w2r.w, fa[3]);
  }
  redf[fc][tok][0] = fa[0]; redf[fc][tok][1] = fa[1];
  redf[fc][tok][2] = fa[2]; redf[fc][tok][3] = fa[3];
  __syncthreads();

  if (fc == 0) {
    float t2[4];
#pragma unroll
    for (int c = 0; c < 4; ++c) {
      float s = b2v[c];
#pragma unroll
      for (int k = 0; k < 8; ++k) s += redf[k][tok][c];
      t2[c] = ress[tok][c] + s;
    }
    float y[4];
    ln4(t2, g2, be2, y);
    if (last) {
      outp[gq] = fmaf(y[3], Wfc[3], fmaf(y[2], Wfc[2], fmaf(y[1], Wfc[1], fmaf(y[0], Wfc[0], bfc[0]))));
    } else {
      *(float4*)(Xout + (size_t)gq*4) = make_float4(y[0], y[1], y[2], y[3]);
    }
  }
}

extern "C" void kernel_launch(void* const* d_in, const int* in_sizes, int n_in,
                              void* d_out, int out_size, void* d_ws, size_t ws_size,
                              hipStream_t stream)
{
  const float* KEY   = (const float*)d_in[0];
  const float* VALUE = (const float*)d_in[1];
  const float* Wq  = (const float*)d_in[2];
  const float* bq  = (const float*)d_in[3];
  const float* Wk  = (const float*)d_in[4];
  const float* bk  = (const float*)d_in[5];
  const float* Wv  = (const float*)d_in[6];
  const float* bv  = (const float*)d_in[7];
  const float* Wo  = (const float*)d_in[8];
  const float* bo  = (const float*)d_in[9];
  const float* bw  = (const float*)d_in[10];
  const float* g1  = (const float*)d_in[11];
  const float* be1 = (const float*)d_in[12];
  const float* W1  = (const float*)d_in[13];
  const float* b1  = (const float*)d_in[14];
  const float* W2  = (const float*)d_in[15];
  const float* b2  = (const float*)d_in[16];
  const float* g2  = (const float*)d_in[17];
  const float* be2 = (const float*)d_in[18];
  const float* Wfc = (const float*)d_in[19];
  const float* bfc = (const float*)d_in[20];
  float* out = (float*)d_out;

  float* w    = (float*)d_ws;
  float* sm   = w;              // 128
  float* w1t  = w + 128;        // 12288
  float* X0   = w + 12416;      // 131072
  float* X1   = w + 143488;     // 131072
  float* part = w + 274560;     // 2097152

  prep_kernel<<<130, 256, 0, stream>>>(KEY, VALUE, Wq, bq, Wk, bk, Wv, bv, Wo, bw,
                                       W1, b1, W2, sm, w1t, X0);

  // layer 0
  attn_kernel<<<512, 256, 0, stream>>>(X0, sm, part);
  combine_kernel<<<512, 512, 0, stream>>>(part, X0, w1t,
      bo, g1, be1, b2, g2, be2,
      X1, Wfc, bfc, out, 0);

  // layer 1
  attn_kernel<<<512, 256, 0, stream>>>(X1, sm + 64, part);
  combine_kernel<<<512, 512, 0, stream>>>(part, X1, w1t + FF*12,
      bo + 4, g1 + 4, be1 + 4, b2 + 4, g2 + 4, be2 + 4,
      X0, Wfc, bfc, out, 1);
}